// Round 5
// baseline (52.592 us; speedup 1.0000x reference)
//
#include <hip/hip_runtime.h>

#define HID 1024
#define BATCH 256
#define KTASK 4096
#define TPB 8             // tasks per block
#define NCOL 64           // 8 tasks * 8 hidden units
#define KC 64             // k per step
#define NSTEPS 16
#define STRIDE 144        // LDS row stride bytes (128 data + 16 pad)
#define BUFSZ (NCOL * STRIDE)

typedef __bf16 bf16x8 __attribute__((ext_vector_type(8)));
typedef __bf16 bf16x4 __attribute__((ext_vector_type(4)));
typedef float f32x4 __attribute__((ext_vector_type(4)));

static __device__ __forceinline__ bf16x8 cvt8(const float4& a, const float4& b) {
    bf16x8 r;
    r[0] = (__bf16)a.x; r[1] = (__bf16)a.y; r[2] = (__bf16)a.z; r[3] = (__bf16)a.w;
    r[4] = (__bf16)b.x; r[5] = (__bf16)b.y; r[6] = (__bf16)b.z; r[7] = (__bf16)b.w;
    return r;
}

__global__ __launch_bounds__(256, 4)
void cvt_emb_kernel(const float* __restrict__ emb, __bf16* __restrict__ dst) {
    int i = (blockIdx.x * 256 + threadIdx.x) * 4;
    float4 v = *(const float4*)(emb + i);
    bf16x4 r;
    r[0] = (__bf16)v.x; r[1] = (__bf16)v.y; r[2] = (__bf16)v.z; r[3] = (__bf16)v.w;
    *(bf16x4*)(dst + i) = r;
}

// 512 threads = 8 waves; wave w owns rows w*32..+31 (2 M-tiles), all 64 cols.
// Full batch per block (W1 fetched once kernel-wide); 3-slot W prefetch:
// step s issues W(s+3), LDS-writes W(s+1)  ->  ~64B/thread HBM in flight.
__global__ __launch_bounds__(512, 4)
void mtc_kernel(const __bf16* __restrict__ embb, const float* __restrict__ W1,
                const float* __restrict__ b1, const float* __restrict__ W2,
                const float* __restrict__ b2, const int* __restrict__ tids,
                float* __restrict__ out)
{
    __shared__ __align__(16) char wbuf[2 * BUFSZ];   // 18 KB

    const int t = threadIdx.x;
    const int lane = t & 63;
    const int w = t >> 6;                // 0..7
    const int blk = blockIdx.x;          // task-group 0..511

    // ---- W1 staging: row srow = (task tl, o); k-eighth sq (8 floats each)
    const int srow = t >> 3;             // 0..63
    const int sq   = t & 7;              // 0..7
    const int stask = tids[blk * TPB + (srow >> 3)];
    const float* sgp = W1 + (size_t)stask * (8 * HID) + (size_t)(srow & 7) * HID + sq * 8;
    char* const swr = &wbuf[0] + srow * STRIDE + sq * 16;

    // ---- A fragments: wave w rows w*32 + bt*16 + (lane&15)
    const __bf16* agp = embb + (size_t)(w * 32 + (lane & 15)) * HID + (lane >> 4) * 8;
    const int boff = (lane & 15) * STRIDE + (lane >> 4) * 16;

    f32x4 acc[2][4];
    const f32x4 zero = {0.f, 0.f, 0.f, 0.f};
#pragma unroll
    for (int i = 0; i < 2; ++i)
#pragma unroll
        for (int j = 0; j < 4; ++j) acc[i][j] = zero;

    // ---- prologue: W(0)->buf0 now; W(1)->qb, W(2)->qc in flight
    float4 qa0 = *(const float4*)(sgp);
    float4 qa1 = *(const float4*)(sgp + 4);
    *(bf16x8*)swr = cvt8(qa0, qa1);
    float4 qb0 = *(const float4*)(sgp + 1 * KC);
    float4 qb1 = *(const float4*)(sgp + 1 * KC + 4);
    float4 qc0 = *(const float4*)(sgp + 2 * KC);
    float4 qc1 = *(const float4*)(sgp + 2 * KC + 4);
    __syncthreads();

    // step S: read buf RB, write W(S+1) from QW -> buf WB, issue W(S+3) -> QI
#define STEP(S, QW0, QW1, QI0, QI1, RB, WB, ISSUE, WRITE, BAR)                              \
    {                                                                                       \
        bf16x8 a00 = *(const bf16x8*)(agp + (S) * KC);                                      \
        bf16x8 a01 = *(const bf16x8*)(agp + (S) * KC + 32);                                 \
        bf16x8 a10 = *(const bf16x8*)(agp + (S) * KC + 16 * HID);                           \
        bf16x8 a11 = *(const bf16x8*)(agp + (S) * KC + 16 * HID + 32);                      \
        if (ISSUE) {                                                                        \
            QI0 = *(const float4*)(sgp + ((S) + 3) * KC);                                   \
            QI1 = *(const float4*)(sgp + ((S) + 3) * KC + 4);                               \
        }                                                                                   \
        const char* rb = &wbuf[0] + (RB) * BUFSZ;                                           \
        bf16x8 b00 = *(const bf16x8*)(rb + 0 * (16 * STRIDE) + boff);                       \
        bf16x8 b01 = *(const bf16x8*)(rb + 0 * (16 * STRIDE) + boff + 64);                  \
        bf16x8 b10 = *(const bf16x8*)(rb + 1 * (16 * STRIDE) + boff);                       \
        bf16x8 b11 = *(const bf16x8*)(rb + 1 * (16 * STRIDE) + boff + 64);                  \
        bf16x8 b20 = *(const bf16x8*)(rb + 2 * (16 * STRIDE) + boff);                       \
        bf16x8 b21 = *(const bf16x8*)(rb + 2 * (16 * STRIDE) + boff + 64);                  \
        bf16x8 b30 = *(const bf16x8*)(rb + 3 * (16 * STRIDE) + boff);                       \
        bf16x8 b31 = *(const bf16x8*)(rb + 3 * (16 * STRIDE) + boff + 64);                  \
        if (WRITE) *(bf16x8*)(swr + (WB) * BUFSZ) = cvt8(QW0, QW1);                         \
        acc[0][0] = __builtin_amdgcn_mfma_f32_16x16x32_bf16(a00, b00, acc[0][0], 0, 0, 0);  \
        acc[0][1] = __builtin_amdgcn_mfma_f32_16x16x32_bf16(a00, b10, acc[0][1], 0, 0, 0);  \
        acc[0][2] = __builtin_amdgcn_mfma_f32_16x16x32_bf16(a00, b20, acc[0][2], 0, 0, 0);  \
        acc[0][3] = __builtin_amdgcn_mfma_f32_16x16x32_bf16(a00, b30, acc[0][3], 0, 0, 0);  \
        acc[1][0] = __builtin_amdgcn_mfma_f32_16x16x32_bf16(a10, b00, acc[1][0], 0, 0, 0);  \
        acc[1][1] = __builtin_amdgcn_mfma_f32_16x16x32_bf16(a10, b10, acc[1][1], 0, 0, 0);  \
        acc[1][2] = __builtin_amdgcn_mfma_f32_16x16x32_bf16(a10, b20, acc[1][2], 0, 0, 0);  \
        acc[1][3] = __builtin_amdgcn_mfma_f32_16x16x32_bf16(a10, b30, acc[1][3], 0, 0, 0);  \
        acc[0][0] = __builtin_amdgcn_mfma_f32_16x16x32_bf16(a01, b01, acc[0][0], 0, 0, 0);  \
        acc[0][1] = __builtin_amdgcn_mfma_f32_16x16x32_bf16(a01, b11, acc[0][1], 0, 0, 0);  \
        acc[0][2] = __builtin_amdgcn_mfma_f32_16x16x32_bf16(a01, b21, acc[0][2], 0, 0, 0);  \
        acc[0][3] = __builtin_amdgcn_mfma_f32_16x16x32_bf16(a01, b31, acc[0][3], 0, 0, 0);  \
        acc[1][0] = __builtin_amdgcn_mfma_f32_16x16x32_bf16(a11, b01, acc[1][0], 0, 0, 0);  \
        acc[1][1] = __builtin_amdgcn_mfma_f32_16x16x32_bf16(a11, b11, acc[1][1], 0, 0, 0);  \
        acc[1][2] = __builtin_amdgcn_mfma_f32_16x16x32_bf16(a11, b21, acc[1][2], 0, 0, 0);  \
        acc[1][3] = __builtin_amdgcn_mfma_f32_16x16x32_bf16(a11, b31, acc[1][3], 0, 0, 0);  \
        if (BAR) __syncthreads();                                                           \
    }

    // W(j) lives in slot j%3 (qa,qb,qc). 6-step macro-cycle, executed twice: s=0..11
    for (int i = 0; i < 2; ++i) {
        const int s = 6 * i;
        STEP(s + 0, qb0, qb1, qa0, qa1, 0, 1, 1, 1, 1)
        STEP(s + 1, qc0, qc1, qb0, qb1, 1, 0, 1, 1, 1)
        STEP(s + 2, qa0, qa1, qc0, qc1, 0, 1, 1, 1, 1)
        STEP(s + 3, qb0, qb1, qa0, qa1, 1, 0, 1, 1, 1)
        STEP(s + 4, qc0, qc1, qb0, qb1, 0, 1, 1, 1, 1)
        STEP(s + 5, qa0, qa1, qc0, qc1, 1, 0, 1, 1, 1)
    }
    // tail: s = 12 (issues W15), 13, 14 (no issue), 15 (read-only, no barrier)
    STEP(12, qb0, qb1, qa0, qa1, 0, 1, 1, 1, 1)
    STEP(13, qc0, qc1, qb0, qb1, 1, 0, 0, 1, 1)
    STEP(14, qa0, qa1, qb0, qb1, 0, 1, 0, 1, 1)
    STEP(15, qa0, qa1, qb0, qb1, 1, 0, 0, 0, 0)
#undef STEP

    // ---- epilogue: +b1, relu, *w2, shuffle-reduce over o (8 lanes), +b2, store
    const int col = lane & 15;
    const int rgrp = lane >> 4;
    const int o = col & 7;
#pragma unroll
    for (int nt = 0; nt < 4; ++nt) {
        const int tl = nt * 2 + (col >> 3);       // task-local 0..7
        const int task = tids[blk * TPB + tl];
        const float bb1 = b1[task * 8 + o];
        const float ww2 = W2[task * 8 + o];
#pragma unroll
        for (int bt = 0; bt < 2; ++bt) {
            float v[4];
#pragma unroll
            for (int r = 0; r < 4; ++r) {
                float x = acc[bt][nt][r] + bb1;
                x = x > 0.f ? x : 0.f;
                v[r] = x * ww2;
            }
#pragma unroll
            for (int m = 1; m <= 4; m <<= 1) {
#pragma unroll
                for (int r = 0; r < 4; ++r) v[r] += __shfl_xor(v[r], m, 64);
            }
            if ((lane & 7) == 0) {
                const float bb2 = b2[task];
                const int brow = w * 32 + bt * 16 + rgrp * 4;
                float4 o4 = make_float4(v[0] + bb2, v[1] + bb2, v[2] + bb2, v[3] + bb2);
                *(float4*)(out + (size_t)(blk * TPB + tl) * BATCH + brow) = o4;
            }
        }
    }
}

extern "C" void kernel_launch(void* const* d_in, const int* in_sizes, int n_in,
                              void* d_out, int out_size, void* d_ws, size_t ws_size,
                              hipStream_t stream) {
    const float* emb = (const float*)d_in[0];
    const float* W1  = (const float*)d_in[1];
    const float* b1  = (const float*)d_in[2];
    const float* W2  = (const float*)d_in[3];
    const float* b2  = (const float*)d_in[4];
    const int*   tid = (const int*)d_in[5];
    float* outp = (float*)d_out;
    __bf16* embb = (__bf16*)d_ws;   // 512 KB

    cvt_emb_kernel<<<dim3(BATCH * HID / (256 * 4)), dim3(256), 0, stream>>>(emb, embb);
    mtc_kernel<<<dim3(KTASK / TPB), dim3(512), 0, stream>>>(embb, W1, b1, W2, b2, tid, outp);
}